// Round 4
// baseline (345.105 us; speedup 1.0000x reference)
//
#include <hip/hip_runtime.h>
#include <stdint.h>
#include <math.h>

// B=2 S=2048 E=1024 H=16 DH=64 ROT=32 CTX=2048
// All d_in / d_out are FLOAT32 (per reference). Internals use bf16 MFMA.
typedef __bf16 bf16x8 __attribute__((ext_vector_type(8)));
typedef float f32x4 __attribute__((ext_vector_type(4)));

__device__ __forceinline__ float bf2f(uint16_t x) {
  unsigned u = ((unsigned)x) << 16;
  float f;
  __builtin_memcpy(&f, &u, 4);
  return f;
}
__device__ __forceinline__ uint16_t f2bf(float f) {
  unsigned u;
  __builtin_memcpy(&u, &f, 4);
  u = u + 0x7FFFu + ((u >> 16) & 1u);
  return (uint16_t)(u >> 16);
}
// load 8 contiguous f32, round to bf16x8
__device__ __forceinline__ bf16x8 cvt8(const float* p) {
  union { bf16x8 v; uint16_t u[8]; } t;
  const float4 lo = *(const float4*)p;
  const float4 hi = *(const float4*)(p + 4);
  t.u[0] = f2bf(lo.x); t.u[1] = f2bf(lo.y); t.u[2] = f2bf(lo.z); t.u[3] = f2bf(lo.w);
  t.u[4] = f2bf(hi.x); t.u[5] = f2bf(hi.y); t.u[6] = f2bf(hi.z); t.u[7] = f2bf(hi.w);
  return t.v;
}

// NT GEMM + bias: C[m,n] = sum_k A[m,k]*W[n,k] + bias[n]
// 128x128 tile, BK=64, 256 threads (2x2 waves of 64x64), z selects operand set.
// A_F32: A is float* (convert to bf16 during staging), else bf16 (uint16_t*).
// C_F32: C is float* (final output), else bf16 workspace.
template <bool A_F32, bool C_F32>
__global__ __launch_bounds__(256) void gemm3_kernel(
    const void* __restrict__ A0, const float* __restrict__ W0,
    const float* __restrict__ b0, void* __restrict__ C0,
    const void* __restrict__ A1, const float* __restrict__ W1,
    const float* __restrict__ b1, void* __restrict__ C1,
    const void* __restrict__ A2, const float* __restrict__ W2,
    const float* __restrict__ b2, void* __restrict__ C2,
    int M, int N, int K) {
  const int z = blockIdx.z;
  const void* Av = z == 0 ? A0 : z == 1 ? A1 : A2;
  const float* W = z == 0 ? W0 : z == 1 ? W1 : W2;
  const float* bias = z == 0 ? b0 : z == 1 ? b1 : b2;
  void* Cv = z == 0 ? C0 : z == 1 ? C1 : C2;

  __shared__ __align__(16) uint16_t As[128 * 64];
  __shared__ __align__(16) uint16_t Bs[128 * 64];
  const int tid = threadIdx.x;
  const int wave = tid >> 6, lane = tid & 63;
  const int quad = lane >> 4, l16 = lane & 15;
  const int bm = blockIdx.y << 7, bn = blockIdx.x << 7;
  const int wm = (wave >> 1) << 6, wn = (wave & 1) << 6;

  f32x4 acc[4][4] = {};

  for (int k0 = 0; k0 < K; k0 += 64) {
    // load tile to registers (bf16-converted), then stage to LDS
    bf16x8 ar[4], wr[4];
#pragma unroll
    for (int i = 0; i < 4; i++) {
      const int c = i * 256 + tid;                // chunk id, 8 elems each
      const int r = c >> 3, cb = (c & 7) * 8;     // row / col-elem within 64
      if (A_F32)
        ar[i] = cvt8((const float*)Av + (size_t)(bm + r) * K + k0 + cb);
      else
        ar[i] = *(const bf16x8*)((const uint16_t*)Av + (size_t)(bm + r) * K + k0 + cb);
      wr[i] = cvt8(W + (size_t)(bn + r) * K + k0 + cb);
    }
    if (k0) __syncthreads();
#pragma unroll
    for (int i = 0; i < 4; i++) {
      const int c = i * 256 + tid;
      *(bf16x8*)(As + c * 8) = ar[i];             // elem off c*8 == r*64+cb
      *(bf16x8*)(Bs + c * 8) = wr[i];
    }
    __syncthreads();
#pragma unroll
    for (int s = 0; s < 2; s++) {
      bf16x8 af[4], bfr[4];
#pragma unroll
      for (int i = 0; i < 4; i++) {
        af[i]  = *(const bf16x8*)(As + (wm + i * 16 + l16) * 64 + s * 32 + quad * 8);
        bfr[i] = *(const bf16x8*)(Bs + (wn + i * 16 + l16) * 64 + s * 32 + quad * 8);
      }
#pragma unroll
      for (int i = 0; i < 4; i++)
#pragma unroll
        for (int j = 0; j < 4; j++)
          acc[i][j] = __builtin_amdgcn_mfma_f32_16x16x32_bf16(af[i], bfr[j], acc[i][j], 0, 0, 0);
    }
  }
#pragma unroll
  for (int j = 0; j < 4; j++) {
    const int n = bn + wn + j * 16 + l16;
    const float bj = bias[n];
#pragma unroll
    for (int i = 0; i < 4; i++) {
      const int m0 = bm + wm + i * 16 + quad * 4;
#pragma unroll
      for (int r = 0; r < 4; r++) {
        const float v = acc[i][j][r] + bj;
        if (C_F32) ((float*)Cv)[(size_t)(m0 + r) * N + n] = v;
        else       ((uint16_t*)Cv)[(size_t)(m0 + r) * N + n] = f2bf(v);
      }
    }
  }
}

// RoPE in place on bf16 Q and K: first 32 dims of each head, interleaved pairs.
// libm sincosf/expf (accurate argument reduction; angles reach ~2047 rad).
__global__ __launch_bounds__(256) void rope_kernel(uint16_t* __restrict__ Q,
                                                   uint16_t* __restrict__ K) {
  const int tid = blockIdx.x * 256 + threadIdx.x;  // B*S*H*16 = 1048576
  const int i = tid & 15;
  const int h = (tid >> 4) & 15;
  const int s = (tid >> 8) & 2047;
  const int b = tid >> 19;
  const size_t base = ((size_t)(b * 2048 + s) * 1024) + h * 64 + 2 * i;
  const float inv = expf(-0.5756462732485115f * (float)i);  // 10000^(-i/16)
  const float ang = (float)s * inv;
  float sn, c;
  sincosf(ang, &sn, &c);
  {
    float x0 = bf2f(Q[base]), x1 = bf2f(Q[base + 1]);
    Q[base]     = f2bf(x0 * c - x1 * sn);
    Q[base + 1] = f2bf(x1 * c + x0 * sn);
  }
  {
    float x0 = bf2f(K[base]), x1 = bf2f(K[base + 1]);
    K[base]     = f2bf(x0 * c - x1 * sn);
    K[base + 1] = f2bf(x1 * c + x0 * sn);
  }
}

// Flash attention, causal. 1 block = (b, h, 64 q rows); wave owns 16 q rows.
// All operands bf16 workspace.
__global__ __launch_bounds__(256) void flash_kernel(const uint16_t* __restrict__ Q,
                                                    const uint16_t* __restrict__ K,
                                                    const uint16_t* __restrict__ V,
                                                    uint16_t* __restrict__ AO) {
  const int bx = blockIdx.x;
  const int qt = bx & 31;         // q tile (S/64 = 32)
  const int h = (bx >> 5) & 15;
  const int b = bx >> 9;
  const int tid = threadIdx.x;
  const int wave = tid >> 6, lane = tid & 63;
  const int quad = lane >> 4, l16 = lane & 15;

  __shared__ __align__(16) uint16_t Ks[64 * 64];      // [n][d]
  __shared__ __align__(16) uint16_t Vt[64 * 72];      // [d][n], padded
  __shared__ __align__(16) uint16_t Ps[4][16 * 72];   // per-wave P, padded

  // Q fragments (A-operand layout), pre-scaled by 1/8 (exact in bf16)
  const int qrow = qt * 64 + wave * 16 + l16;
  const size_t qoff = ((size_t)(b * 2048 + qrow) * 1024) + h * 64;
  bf16x8 qf[2];
#pragma unroll
  for (int s = 0; s < 2; s++) {
    union { bf16x8 v; uint16_t u[8]; } t;
    t.v = *(const bf16x8*)(Q + qoff + s * 32 + quad * 8);
#pragma unroll
    for (int j = 0; j < 8; j++) t.u[j] = f2bf(bf2f(t.u[j]) * 0.125f);
    qf[s] = t.v;
  }

  float m_i[4], l_i[4];
  f32x4 o[4] = {};
#pragma unroll
  for (int r = 0; r < 4; r++) { m_i[r] = -1e30f; l_i[r] = 0.f; }

  const int nkt = qt + 1;
  for (int kt = 0; kt < nkt; kt++) {
    // K tile rows + V tile (to be transposed) -> registers
    bf16x8 kr[2], vr[2];
#pragma unroll
    for (int i = 0; i < 2; i++) {
      const int c = i * 256 + tid;
      const int n = c >> 3, d8 = (c & 7) * 8;
      kr[i] = *(const bf16x8*)(K + ((size_t)(b * 2048 + kt * 64 + n) * 1024) + h * 64 + d8);
      const int vd0 = (i * 4 + wave) * 8;
      vr[i] = *(const bf16x8*)(V + ((size_t)(b * 2048 + kt * 64 + lane) * 1024) + h * 64 + vd0);
    }
    if (kt) __syncthreads();
#pragma unroll
    for (int i = 0; i < 2; i++) {
      const int c = i * 256 + tid;
      *(bf16x8*)(Ks + c * 8) = kr[i];             // Ks[n][d] row-major
      // V transposed into Vt[d][n] (lane = n -> <=2-way bank aliasing)
      union { bf16x8 v; uint16_t u[8]; } t;
      t.v = vr[i];
      const int vd0 = (i * 4 + wave) * 8;
#pragma unroll
      for (int j = 0; j < 8; j++) Vt[(vd0 + j) * 72 + lane] = t.u[j];
    }
    __syncthreads();

    // S = Q K^T (pre-scaled); n-tiles t of 16 cols each
    f32x4 sacc[4] = {};
#pragma unroll
    for (int s = 0; s < 2; s++) {
#pragma unroll
      for (int t = 0; t < 4; t++) {
        bf16x8 kf = *(const bf16x8*)(Ks + (t * 16 + l16) * 64 + s * 32 + quad * 8);
        sacc[t] = __builtin_amdgcn_mfma_f32_16x16x32_bf16(qf[s], kf, sacc[t], 0, 0, 0);
      }
    }
    // causal mask (only diagonal tile needs it; kv base <= q base always)
    if (kt == qt) {
#pragma unroll
      for (int t = 0; t < 4; t++)
#pragma unroll
        for (int r = 0; r < 4; r++) {
          const int kg = kt * 64 + t * 16 + l16;
          const int qg = qt * 64 + wave * 16 + quad * 4 + r;
          if (kg > qg) sacc[t][r] = -1e30f;
        }
    }
    // online softmax; a row's 16 cols live in lanes differing in bits 0..3
#pragma unroll
    for (int r = 0; r < 4; r++) {
      float mx = fmaxf(fmaxf(sacc[0][r], sacc[1][r]), fmaxf(sacc[2][r], sacc[3][r]));
      mx = fmaxf(mx, __shfl_xor(mx, 1));
      mx = fmaxf(mx, __shfl_xor(mx, 2));
      mx = fmaxf(mx, __shfl_xor(mx, 4));
      mx = fmaxf(mx, __shfl_xor(mx, 8));
      const float mn = fmaxf(m_i[r], mx);
      const float alpha = __expf(m_i[r] - mn);
      m_i[r] = mn;
      float rs = 0.f;
#pragma unroll
      for (int t = 0; t < 4; t++) {
        const float p = __expf(sacc[t][r] - mn);
        sacc[t][r] = p;
        rs += p;
      }
      rs += __shfl_xor(rs, 1);
      rs += __shfl_xor(rs, 2);
      rs += __shfl_xor(rs, 4);
      rs += __shfl_xor(rs, 8);
      l_i[r] = l_i[r] * alpha + rs;
#pragma unroll
      for (int t = 0; t < 4; t++) o[t][r] *= alpha;
    }
    // P: C/D layout -> LDS -> A-operand layout (per-wave region, in-order DS)
#pragma unroll
    for (int t = 0; t < 4; t++)
#pragma unroll
      for (int r = 0; r < 4; r++)
        Ps[wave][(quad * 4 + r) * 72 + t * 16 + l16] = f2bf(sacc[t][r]);
#pragma unroll
    for (int s = 0; s < 2; s++) {
      const bf16x8 pa = *(const bf16x8*)(&Ps[wave][l16 * 72 + s * 32 + quad * 8]);
#pragma unroll
      for (int t = 0; t < 4; t++) {
        const bf16x8 vb = *(const bf16x8*)(Vt + (t * 16 + l16) * 72 + s * 32 + quad * 8);
        o[t] = __builtin_amdgcn_mfma_f32_16x16x32_bf16(pa, vb, o[t], 0, 0, 0);
      }
    }
  }
  // normalize + write (b, s, h*64+dh) bf16
#pragma unroll
  for (int t = 0; t < 4; t++)
#pragma unroll
    for (int r = 0; r < 4; r++) {
      const int qg = qt * 64 + wave * 16 + quad * 4 + r;
      const float val = o[t][r] / l_i[r];
      AO[((size_t)(b * 2048 + qg) * 1024) + h * 64 + t * 16 + l16] = f2bf(val);
    }
}

extern "C" void kernel_launch(void* const* d_in, const int* in_sizes, int n_in,
                              void* d_out, int out_size, void* d_ws, size_t ws_size,
                              hipStream_t stream) {
  const float* query = (const float*)d_in[0];
  const float* key   = (const float*)d_in[1];
  const float* value = (const float*)d_in[2];
  const float* Wq = (const float*)d_in[3];
  const float* bq = (const float*)d_in[4];
  const float* Wk = (const float*)d_in[5];
  const float* bk = (const float*)d_in[6];
  const float* Wv = (const float*)d_in[7];
  const float* bv = (const float*)d_in[8];
  const float* Wo = (const float*)d_in[9];
  const float* bo = (const float*)d_in[10];
  float* out = (float*)d_out;

  uint16_t* ws = (uint16_t*)d_ws;
  uint16_t* Qb  = ws;                         // 4M bf16 elems (8 MB)
  uint16_t* Kb  = ws + (size_t)4194304;
  uint16_t* Vb  = ws + (size_t)8388608;
  uint16_t* AOb = ws + (size_t)12582912;      // total 32 MB of d_ws

  dim3 blk(256);
  gemm3_kernel<true, false><<<dim3(8, 32, 3), blk, 0, stream>>>(
      query, Wq, bq, Qb,
      key,   Wk, bk, Kb,
      value, Wv, bv, Vb,
      4096, 1024, 1024);
  rope_kernel<<<dim3(4096), blk, 0, stream>>>(Qb, Kb);
  flash_kernel<<<dim3(1024), blk, 0, stream>>>(Qb, Kb, Vb, AOb);
  gemm3_kernel<false, true><<<dim3(8, 32, 1), blk, 0, stream>>>(
      AOb, Wo, bo, out,
      AOb, Wo, bo, out,
      AOb, Wo, bo, out,
      4096, 1024, 1024);
}